// Round 17
// baseline (8919.232 us; speedup 1.0000x reference)
//
#include <hip/hip_runtime.h>
#include <math.h>

#define BB 64
#define TT 512
#define FF 32
#define HH 512
#define OO 680

typedef _Float16 half8 __attribute__((ext_vector_type(8)));
typedef float f32x4 __attribute__((ext_vector_type(4)));

// ---- ws layout: act slabs in MFMA-B-fragment tile order, ping-pong by epoch parity ----
#define H1S_OFF 0u          // 2 x 65536  (h1, 512 cols)
#define C1S_OFF 131072u     // 2 x 65536  (c1, 512 cols)
#define H2S_OFF 262144u     // 2 x 90112  (h2, 704 padded cols)
#define BAR_OFF 442368u
#define MEMSET_BYTES 443648u

#define NBLK 64
#define LDS_BYTES 151552u   // L1 weights 34KB + L2 weights 114KB
#define L2W_OFF 34816u

// bar dwords: 8 arrival counters (one 128B line each) + 8 packed flags (one line)
// Arrival group is CONTIGUOUS: block bk -> group bk>>3 (8 blocks each), so
// group g's flag covers L1 cols [64g,64g+64) and L2 cols [96g,96g+96).
#define CNT(g) ((g)*32)
#define FLG    256

__device__ __forceinline__ float sigf(float x) { return 1.f / (1.f + expf(-x)); }

__device__ __forceinline__ unsigned long long aload8(const void* p) {
    return __hip_atomic_load((const unsigned long long*)p, __ATOMIC_RELAXED, __HIP_MEMORY_SCOPE_AGENT);
}
__device__ __forceinline__ void astore8(void* p, unsigned long long v) {
    __hip_atomic_store((unsigned long long*)p, v, __ATOMIC_RELAXED, __HIP_MEMORY_SCOPE_AGENT);
}
__device__ __forceinline__ void astore32(unsigned* p, unsigned v) {
    __hip_atomic_store(p, v, __ATOMIC_RELAXED, __HIP_MEMORY_SCOPE_AGENT);
}
__device__ __forceinline__ half8 ld_act(const char* p) {
    union { unsigned long long u[2]; half8 h; } t;
    t.u[0] = aload8(p); t.u[1] = aload8(p + 8);
    return t.h;
}
__device__ __forceinline__ unsigned pack2h(float a, float b) {
    union { _Float16 h[2]; unsigned u; } t;
    t.h[0] = (_Float16)a; t.h[1] = (_Float16)b; return t.u;
}
__device__ __forceinline__ unsigned long long pack4h(float a, float b, float c, float d) {
    union { _Float16 h[4]; unsigned long long u; } t;
    t.h[0] = (_Float16)a; t.h[1] = (_Float16)b; t.h[2] = (_Float16)c; t.h[3] = (_Float16)d;
    return t.u;
}
__device__ __forceinline__ size_t slab_waddr(int cc, int b) {
    return (size_t)((cc >> 5) * 4 + (b >> 4)) * 1024
         + (size_t)((((cc >> 3) & 3) * 16 + (b & 15))) * 16
         + (size_t)(cc & 7) * 2;
}

// ---- per-wave cached flag poll: one 32B read refreshes all 8 caches ----
#define POLLG(fcg) \
    if ((fcg) < tgt) { for (;;) { \
        const unsigned long long q0 = aload8(bar + FLG);     \
        const unsigned long long q1 = aload8(bar + FLG + 2); \
        const unsigned long long q2 = aload8(bar + FLG + 4); \
        const unsigned long long q3 = aload8(bar + FLG + 6); \
        fc0 = (unsigned)q0; fc1 = (unsigned)(q0 >> 32);      \
        fc2 = (unsigned)q1; fc3 = (unsigned)(q1 >> 32);      \
        fc4 = (unsigned)q2; fc5 = (unsigned)(q2 >> 32);      \
        fc6 = (unsigned)q3; fc7 = (unsigned)(q3 >> 32);      \
        if ((fcg) >= tgt) break;                             \
        __builtin_amdgcn_s_sleep(1); } }

#define MFA(off, B, ACC) ACC = __builtin_amdgcn_mfma_f32_16x16x32_f16(*(const half8*)(lds + (size_t)(off) * 1024u + (size_t)l * 16), (B), ACC, 0, 0, 0)
#define MFB(off, B, ACC) ACC = __builtin_amdgcn_mfma_f32_16x16x32_f16(*(const half8*)(lds + L2W_OFF + (size_t)(off) * 1024u + (size_t)l * 16), (B), ACC, 0, 0, 0)

// consume one h1 / c1 / h2 k-tile (load + its MFMAs), tile index t
#define H1T(t) { const half8 u = ld_act(h1p + (size_t)((t) * 4 + wv) * 1024u); \
                 MFA(((t) + 1) * 2, u, a10); MFA(((t) + 1) * 2 + 1, u, a11); }
#define C1T(t) { const half8 u = ld_act(c1p + (size_t)((t) * 4 + wv) * 1024u); \
                 MFB((t) * 3, u, a20); MFB((t) * 3 + 1, u, a21); MFB((t) * 3 + 2, u, a22); }
#define H2T(t) { const half8 u = ld_act(h2p + (size_t)((t) * 4 + wv) * 1024u); \
                 MFB((16 + (t)) * 3, u, a20); MFB((16 + (t)) * 3 + 1, u, a21); MFB((16 + (t)) * 3 + 2, u, a22); }

// group g ready => h1/c1 tiles {2g,2g+1}; h2 tiles {3g..3g+2} (g<7) or {21} (g==7)
#define GRP(g, fcg) \
    POLLG(fcg); \
    if (s < TT) { H1T(2 * (g)); H1T(2 * (g) + 1); } \
    if (s >= 1) { C1T(2 * (g)); C1T(2 * (g) + 1); \
        if ((g) < 7) { H2T(3 * (g)); H2T(3 * (g) + 1); H2T(3 * (g) + 2); } \
        else         { H2T(21); } }

// Merged persistent MFMA kernel, 64 blocks x 256 threads, ONE sync domain,
// fine-grained per-producer-group consumption (stragglers overlapped).
__global__ __launch_bounds__(256, 1)
void rnn_merged(const float* __restrict__ data,
    const float* __restrict__ Wih1, const float* __restrict__ Whh1,
    const float* __restrict__ bih1, const float* __restrict__ bhh1,
    const float* __restrict__ Wih2, const float* __restrict__ Whh2,
    const float* __restrict__ bih2, const float* __restrict__ bhh2,
    char* __restrict__ wsb, float* __restrict__ out)
{
    extern __shared__ char lds[];
    const int tid = threadIdx.x, wv = tid >> 6, l = tid & 63;
    const int hi = l >> 4, lo = l & 15;
    const int bk = blockIdx.x;
    unsigned* bar = (unsigned*)(wsb + BAR_OFF);
    const int b = wv * 16 + lo;

    // ---- one-time weight conversion fp32 -> fp16 into LDS (A-fragment tiles) ----
    for (int u = tid; u < 34 * 256; u += 256) {
        const int tt = u >> 8, w = u & 255;
        const int ks = tt >> 1, q = tt & 1;
        const int ll = w >> 2, jj = w & 3;
        const int fq = q * 16 + (ll & 15);
        const int col = bk * 8 + (fq >> 2);
        const int gate = fq & 3;
        const int grow = gate * HH + col;
        const int k = ks * 32 + (ll >> 4) * 8 + jj * 2;
        const float v0 = (k < FF)     ? Wih1[(size_t)grow * FF + k]     : Whh1[(size_t)grow * HH + k - FF];
        const float v1 = (k + 1 < FF) ? Wih1[(size_t)grow * FF + k + 1] : Whh1[(size_t)grow * HH + k + 1 - FF];
        ((unsigned*)lds)[tt * 256 + w] = pack2h(v0, v1);
    }
    for (int u = tid; u < 114 * 256; u += 256) {
        const int tt = u >> 8, w = u & 255;
        const int ks = tt / 3, q = tt - ks * 3;
        const int ll = w >> 2, jj = w & 3;
        const int fq = q * 16 + (ll & 15);
        const int col = bk * 12 + (fq >> 2);
        const int gate = fq & 3;
        const int k = ks * 32 + (ll >> 4) * 8 + jj * 2;
        float v0 = 0.f, v1 = 0.f;
        if (col < OO) {
            if (k < HH) v0 = Wih2[((size_t)gate * OO + col) * HH + k];
            else if (k < 1192) v0 = Whh2[((size_t)gate * OO + col) * OO + k - HH];
            if (k + 1 < HH) v1 = Wih2[((size_t)gate * OO + col) * HH + k + 1];
            else if (k + 1 < 1192) v1 = Whh2[((size_t)gate * OO + col) * OO + k + 1 - HH];
        }
        ((unsigned*)(lds + L2W_OFF))[tt * 256 + w] = pack2h(v0, v1);
    }
    __syncthreads();

    // ---- bias hoist (lane-local) ----
    float bs1[2][4], bs2[3][4];
    #pragma unroll
    for (int q = 0; q < 2; ++q) {
        const int col = bk * 8 + q * 4 + hi;
        #pragma unroll
        for (int g = 0; g < 4; ++g) bs1[q][g] = bih1[g * HH + col] + bhh1[g * HH + col];
    }
    #pragma unroll
    for (int q = 0; q < 3; ++q) {
        const int col = bk * 12 + q * 4 + hi;
        const bool ok = col < OO;
        #pragma unroll
        for (int g = 0; g < 4; ++g) bs2[q][g] = ok ? (bih2[g * OO + col] + bhh2[g * OO + col]) : 0.f;
    }
    float cr1[2] = {0.f, 0.f};
    float cr2[3] = {0.f, 0.f, 0.f};
    unsigned fc0 = 0, fc1 = 0, fc2 = 0, fc3 = 0, fc4 = 0, fc5 = 0, fc6 = 0, fc7 = 0;

    for (int s = 0; s <= TT; ++s) {
        const int wr = s & 1, rd = wr ^ 1;
        const unsigned tgt = (unsigned)s;
        // ---- L1 x-part first (independent of recurrence) ----
        f32x4 a10 = {0,0,0,0}, a11 = {0,0,0,0};
        f32x4 a20 = {0,0,0,0}, a21 = {0,0,0,0}, a22 = {0,0,0,0};
        if (s < TT) {
            const float* xp = data + (size_t)b * (TT * FF) + (size_t)s * FF + hi * 8;
            const float4 xa = *(const float4*)xp;
            const float4 xb4 = *(const float4*)(xp + 4);
            half8 bx;
            bx[0] = (_Float16)xa.x; bx[1] = (_Float16)xa.y; bx[2] = (_Float16)xa.z; bx[3] = (_Float16)xa.w;
            bx[4] = (_Float16)xb4.x; bx[5] = (_Float16)xb4.y; bx[6] = (_Float16)xb4.z; bx[7] = (_Float16)xb4.w;
            MFA(0, bx, a10); MFA(1, bx, a11);
        }
        const char* h1p = wsb + H1S_OFF + (size_t)rd * 65536u + (size_t)l * 16;
        const char* c1p = wsb + C1S_OFF + (size_t)rd * 65536u + (size_t)l * 16;
        const char* h2p = wsb + H2S_OFF + (size_t)rd * 90112u + (size_t)l * 16;

        // ---- fine-grained consumption: per producer-group poll -> consume ----
        GRP(0, fc0); GRP(1, fc1); GRP(2, fc2); GRP(3, fc3);
        GRP(4, fc4); GRP(5, fc5); GRP(6, fc6); GRP(7, fc7);

        float pend[4]; float* pendP = nullptr;

        // ================= L1 epilogue: step s =================
        if (s < TT) {
            float cn1[2], hn1[2];
            #pragma unroll
            for (int q = 0; q < 2; ++q) {
                const f32x4 a = (q == 0) ? a10 : a11;
                const float ig = sigf(a[0] + bs1[q][0]);
                const float fg = sigf(a[1] + bs1[q][1]);
                const float gg = tanhf(a[2] + bs1[q][2]);
                const float og = sigf(a[3] + bs1[q][3]);
                const float c = fg * cr1[q] + ig * gg;
                cr1[q] = c;
                cn1[q] = c; hn1[q] = og * tanhf(c);
            }
            char* h1w = wsb + H1S_OFF + (size_t)wr * 65536u;
            char* c1w = wsb + C1S_OFF + (size_t)wr * 65536u;
            #pragma unroll
            for (int q = 0; q < 2; ++q) {
                const float h0 = __shfl(hn1[q], lo), h1v = __shfl(hn1[q], 16 + lo);
                const float h2v = __shfl(hn1[q], 32 + lo), h3 = __shfl(hn1[q], 48 + lo);
                const float c0 = __shfl(cn1[q], lo), c1v = __shfl(cn1[q], 16 + lo);
                const float c2v = __shfl(cn1[q], 32 + lo), c3 = __shfl(cn1[q], 48 + lo);
                if (hi == q) {
                    const int cc = bk * 8 + q * 4;
                    const size_t ad = slab_waddr(cc, b);
                    astore8(h1w + ad, pack4h(h0, h1v, h2v, h3));
                    astore8(c1w + ad, pack4h(c0, c1v, c2v, c3));
                }
            }
        }
        // ================= L2 epilogue: step s-1 =================
        if (s >= 1) {
            float cn2[3], hn2[3];
            #pragma unroll
            for (int q = 0; q < 3; ++q) {
                const f32x4 a = (q == 0) ? a20 : (q == 1) ? a21 : a22;
                const float ig = sigf(a[0] + bs2[q][0]);
                const float fg = sigf(a[1] + bs2[q][1]);
                const float gg = tanhf(a[2] + bs2[q][2]);
                const float og = sigf(a[3] + bs2[q][3]);
                const float c = fg * cr2[q] + ig * gg;
                cr2[q] = c;
                cn2[q] = c; hn2[q] = og * tanhf(c);
            }
            char* h2w = wsb + H2S_OFF + (size_t)wr * 90112u;
            #pragma unroll
            for (int q = 0; q < 3; ++q) {
                const float h0 = __shfl(hn2[q], lo), h1v = __shfl(hn2[q], 16 + lo);
                const float h2v = __shfl(hn2[q], 32 + lo), h3 = __shfl(hn2[q], 48 + lo);
                const float c0 = __shfl(cn2[q], lo), c1v = __shfl(cn2[q], 16 + lo);
                const float c2v = __shfl(cn2[q], 32 + lo), c3 = __shfl(cn2[q], 48 + lo);
                if (hi == q) {
                    const int cc = bk * 12 + q * 4;
                    if (cc + 4 <= OO) {
                        astore8(h2w + slab_waddr(cc, b), pack4h(h0, h1v, h2v, h3));
                        pend[0] = c0; pend[1] = c1v; pend[2] = c2v; pend[3] = c3;
                        pendP = out + (size_t)b * (TT * OO) + (size_t)(s - 1) * OO + cc;
                    }
                }
            }
        }
        // ---- single arrival per block (contiguous group bk>>3) ----
        __syncthreads();
        if (s < TT && tid == 0) {
            const int g = bk >> 3;
            const unsigned e = (unsigned)(s + 1);
            const unsigned a = __hip_atomic_fetch_add(bar + CNT(g), 1u, __ATOMIC_RELAXED, __HIP_MEMORY_SCOPE_AGENT);
            if (a == e * 8u - 1u) astore32(bar + FLG + g, e);
        }
        // ---- deferred out store ----
        if (pendP) {
            const f32x4 q4 = {pend[0], pend[1], pend[2], pend[3]};
            __builtin_nontemporal_store(q4, (f32x4*)pendP);
        }
    }
}

extern "C" void kernel_launch(void* const* d_in, const int* in_sizes, int n_in,
                              void* d_out, int out_size, void* d_ws, size_t ws_size,
                              hipStream_t stream)
{
    const float* data = (const float*)d_in[0];
    const float* Wih1 = (const float*)d_in[1];
    const float* Whh1 = (const float*)d_in[2];
    const float* bih1 = (const float*)d_in[3];
    const float* bhh1 = (const float*)d_in[4];
    const float* Wih2 = (const float*)d_in[5];
    const float* Whh2 = (const float*)d_in[6];
    const float* bih2 = (const float*)d_in[7];
    const float* bhh2 = (const float*)d_in[8];
    float* out = (float*)d_out;
    char* wsb  = (char*)d_ws;

    hipFuncSetAttribute((const void*)rnn_merged, hipFuncAttributeMaxDynamicSharedMemorySize, (int)LDS_BYTES);
    hipMemsetAsync(wsb, 0, MEMSET_BYTES, stream);   // slabs + counters/flags: replay-safe
    rnn_merged<<<NBLK, 256, LDS_BYTES, stream>>>(data,
                                                 Wih1, Whh1, bih1, bhh1,
                                                 Wih2, Whh2, bih2, bhh2,
                                                 wsb, out);
}

// Round 18
// 4080.922 us; speedup vs baseline: 2.1856x; 2.1856x over previous
//
#include <hip/hip_runtime.h>
#include <math.h>

#define BB 64
#define TT 512
#define FF 32
#define HH 512
#define OO 680

typedef _Float16 half8 __attribute__((ext_vector_type(8)));
typedef float f32x4 __attribute__((ext_vector_type(4)));

// ---- ws layout: act slabs in MFMA-B-fragment tile order, ping-pong by epoch parity ----
#define H1S_OFF 0u          // 2 x 65536  (h1, 512 cols)
#define C1S_OFF 131072u     // 2 x 65536  (c1, 512 cols)
#define H2S_OFF 262144u     // 2 x 90112  (h2, 704 padded cols)
#define BAR_OFF 442368u     // 64 epoch slots (4 lines, store-only)
#define MEMSET_BYTES 443648u

#define NBLK 64
#define LDS_BYTES 151552u   // L1 weights 34KB + L2 weights 114KB
#define L2W_OFF 34816u

__device__ __forceinline__ float sigf(float x) { return 1.f / (1.f + expf(-x)); }

__device__ __forceinline__ unsigned al32(const unsigned* p) {
    return __hip_atomic_load(p, __ATOMIC_RELAXED, __HIP_MEMORY_SCOPE_AGENT);
}
__device__ __forceinline__ unsigned long long aload8(const void* p) {
    return __hip_atomic_load((const unsigned long long*)p, __ATOMIC_RELAXED, __HIP_MEMORY_SCOPE_AGENT);
}
__device__ __forceinline__ void astore8(void* p, unsigned long long v) {
    __hip_atomic_store((unsigned long long*)p, v, __ATOMIC_RELAXED, __HIP_MEMORY_SCOPE_AGENT);
}
__device__ __forceinline__ void astore32(unsigned* p, unsigned v) {
    __hip_atomic_store(p, v, __ATOMIC_RELAXED, __HIP_MEMORY_SCOPE_AGENT);
}
__device__ __forceinline__ half8 ld_act(const char* p) {
    union { unsigned long long u[2]; half8 h; } t;
    t.u[0] = aload8(p); t.u[1] = aload8(p + 8);
    return t.h;
}
__device__ __forceinline__ unsigned pack2h(float a, float b) {
    union { _Float16 h[2]; unsigned u; } t;
    t.h[0] = (_Float16)a; t.h[1] = (_Float16)b; return t.u;
}
__device__ __forceinline__ unsigned long long pack4h(float a, float b, float c, float d) {
    union { _Float16 h[4]; unsigned long long u; } t;
    t.h[0] = (_Float16)a; t.h[1] = (_Float16)b; t.h[2] = (_Float16)c; t.h[3] = (_Float16)d;
    return t.u;
}
__device__ __forceinline__ size_t slab_waddr(int cc, int b) {
    return (size_t)((cc >> 5) * 4 + (b >> 4)) * 1024
         + (size_t)((((cc >> 3) & 3) * 16 + (b & 15))) * 16
         + (size_t)(cc & 7) * 2;
}

// Merged persistent MFMA kernel: 64 blocks x 256 threads, ONE sync domain.
// Arrival: single relaxed epoch store to slot[bk] (store-only lines, no RMW,
// no flag hop). Wait: wave 0 loads all 64 slots in one instruction and
// shfl-min-reduces; __syncthreads releases the block.
__global__ __launch_bounds__(256, 1)
void rnn_merged(const float* __restrict__ data,
    const float* __restrict__ Wih1, const float* __restrict__ Whh1,
    const float* __restrict__ bih1, const float* __restrict__ bhh1,
    const float* __restrict__ Wih2, const float* __restrict__ Whh2,
    const float* __restrict__ bih2, const float* __restrict__ bhh2,
    char* __restrict__ wsb, float* __restrict__ out)
{
    extern __shared__ char lds[];
    const int tid = threadIdx.x, wv = tid >> 6, l = tid & 63;
    const int hi = l >> 4, lo = l & 15;
    const int bk = blockIdx.x;
    unsigned* bar = (unsigned*)(wsb + BAR_OFF);
    const int b = wv * 16 + lo;                 // this lane's batch

    // ---- one-time: convert weights fp32 -> fp16 into LDS (A-fragment tiles) ----
    // L1: 34 tiles; row fq = q*16 + i; col = bk*8 + fq>>2; gate = fq&3.
    for (int u = tid; u < 34 * 256; u += 256) {
        const int tt = u >> 8, w = u & 255;
        const int ks = tt >> 1, q = tt & 1;
        const int ll = w >> 2, jj = w & 3;
        const int fq = q * 16 + (ll & 15);
        const int col = bk * 8 + (fq >> 2);
        const int gate = fq & 3;
        const int grow = gate * HH + col;
        const int k = ks * 32 + (ll >> 4) * 8 + jj * 2;
        const float v0 = (k < FF)     ? Wih1[(size_t)grow * FF + k]     : Whh1[(size_t)grow * HH + k - FF];
        const float v1 = (k + 1 < FF) ? Wih1[(size_t)grow * FF + k + 1] : Whh1[(size_t)grow * HH + k + 1 - FF];
        ((unsigned*)lds)[tt * 256 + w] = pack2h(v0, v1);
    }
    // L2: 114 tiles; fq = q*16 + i; col = bk*12 + fq>>2; gate = fq&3.
    for (int u = tid; u < 114 * 256; u += 256) {
        const int tt = u >> 8, w = u & 255;
        const int ks = tt / 3, q = tt - ks * 3;
        const int ll = w >> 2, jj = w & 3;
        const int fq = q * 16 + (ll & 15);
        const int col = bk * 12 + (fq >> 2);
        const int gate = fq & 3;
        const int k = ks * 32 + (ll >> 4) * 8 + jj * 2;
        float v0 = 0.f, v1 = 0.f;
        if (col < OO) {
            if (k < HH) v0 = Wih2[((size_t)gate * OO + col) * HH + k];
            else if (k < 1192) v0 = Whh2[((size_t)gate * OO + col) * OO + k - HH];
            if (k + 1 < HH) v1 = Wih2[((size_t)gate * OO + col) * HH + k + 1];
            else if (k + 1 < 1192) v1 = Whh2[((size_t)gate * OO + col) * OO + k + 1 - HH];
        }
        ((unsigned*)(lds + L2W_OFF))[tt * 256 + w] = pack2h(v0, v1);
    }
    __syncthreads();

    // ---- bias hoist: lane-local ----
    float bs1[2][4], bs2[3][4];
    #pragma unroll
    for (int q = 0; q < 2; ++q) {
        const int col = bk * 8 + q * 4 + hi;
        #pragma unroll
        for (int g = 0; g < 4; ++g) bs1[q][g] = bih1[g * HH + col] + bhh1[g * HH + col];
    }
    #pragma unroll
    for (int q = 0; q < 3; ++q) {
        const int col = bk * 12 + q * 4 + hi;
        const bool ok = col < OO;
        #pragma unroll
        for (int g = 0; g < 4; ++g) bs2[q][g] = ok ? (bih2[g * OO + col] + bhh2[g * OO + col]) : 0.f;
    }
    float cr1[2] = {0.f, 0.f};
    float cr2[3] = {0.f, 0.f, 0.f};

    for (int s = 0; s <= TT; ++s) {
        const int wr = s & 1, rd = wr ^ 1;      // slab parity: write s&1, read (s-1)&1
        // ---- L1 x-part: loads + 2 MFMAs BEFORE the wait ----
        f32x4 a10 = {0,0,0,0}, a11 = {0,0,0,0};
        if (s < TT) {
            const float* xp = data + (size_t)b * (TT * FF) + (size_t)s * FF + hi * 8;
            const float4 xa = *(const float4*)xp;
            const float4 xb4 = *(const float4*)(xp + 4);
            half8 bx;
            bx[0] = (_Float16)xa.x; bx[1] = (_Float16)xa.y; bx[2] = (_Float16)xa.z; bx[3] = (_Float16)xa.w;
            bx[4] = (_Float16)xb4.x; bx[5] = (_Float16)xb4.y; bx[6] = (_Float16)xb4.z; bx[7] = (_Float16)xb4.w;
            a10 = __builtin_amdgcn_mfma_f32_16x16x32_f16(*(const half8*)(lds + (size_t)l * 16), bx, a10, 0, 0, 0);
            a11 = __builtin_amdgcn_mfma_f32_16x16x32_f16(*(const half8*)(lds + 1024 + (size_t)l * 16), bx, a11, 0, 0, 0);
        }
        // ---- THE single wait: all 64 slots >= s (wave 0, one load + shfl-min) ----
        if (s > 0) {
            if (wv == 0) {
                for (;;) {
                    unsigned v = al32(bar + l);
                    #pragma unroll
                    for (int off = 32; off > 0; off >>= 1) {
                        const unsigned o = __shfl_xor(v, off);
                        v = (o < v) ? o : v;
                    }
                    if (v >= (unsigned)s) break;
                    __builtin_amdgcn_s_sleep(1);
                }
            }
            __syncthreads();
        }
        float pend[4]; float* pendP = nullptr;   // deferred out store

        // ================= L1 part: step s =================
        if (s < TT) {
            const char* h1p = wsb + H1S_OFF + (size_t)rd * 65536u + (size_t)l * 16;
            half8 bh[16];
            #pragma unroll
            for (int ks = 0; ks < 16; ++ks) bh[ks] = ld_act(h1p + (size_t)(ks * 4 + wv) * 1024);
            #pragma unroll
            for (int ks = 1; ks <= 16; ++ks) {
                a10 = __builtin_amdgcn_mfma_f32_16x16x32_f16(*(const half8*)(lds + (size_t)(ks * 2) * 1024 + (size_t)l * 16), bh[ks - 1], a10, 0, 0, 0);
                a11 = __builtin_amdgcn_mfma_f32_16x16x32_f16(*(const half8*)(lds + (size_t)(ks * 2 + 1) * 1024 + (size_t)l * 16), bh[ks - 1], a11, 0, 0, 0);
            }
            float cn1[2], hn1[2];
            #pragma unroll
            for (int q = 0; q < 2; ++q) {
                const f32x4 a = (q == 0) ? a10 : a11;
                const float ig = sigf(a[0] + bs1[q][0]);
                const float fg = sigf(a[1] + bs1[q][1]);
                const float gg = tanhf(a[2] + bs1[q][2]);
                const float og = sigf(a[3] + bs1[q][3]);
                const float c = fg * cr1[q] + ig * gg;
                cr1[q] = c;
                cn1[q] = c; hn1[q] = og * tanhf(c);
            }
            char* h1w = wsb + H1S_OFF + (size_t)wr * 65536u;
            char* c1w = wsb + C1S_OFF + (size_t)wr * 65536u;
            #pragma unroll
            for (int q = 0; q < 2; ++q) {
                const float h0 = __shfl(hn1[q], lo), h1v = __shfl(hn1[q], 16 + lo);
                const float h2v = __shfl(hn1[q], 32 + lo), h3 = __shfl(hn1[q], 48 + lo);
                const float c0 = __shfl(cn1[q], lo), c1v = __shfl(cn1[q], 16 + lo);
                const float c2v = __shfl(cn1[q], 32 + lo), c3 = __shfl(cn1[q], 48 + lo);
                if (hi == q) {
                    const int cc = bk * 8 + q * 4;
                    const size_t ad = slab_waddr(cc, b);
                    astore8(h1w + ad, pack4h(h0, h1v, h2v, h3));
                    astore8(c1w + ad, pack4h(c0, c1v, c2v, c3));
                }
            }
        }
        // ================= L2 part: step s-1 =================
        if (s >= 1) {
            f32x4 a20 = {0,0,0,0}, a21 = {0,0,0,0}, a22 = {0,0,0,0};
            const char* c1p = wsb + C1S_OFF + (size_t)rd * 65536u + (size_t)l * 16;
            half8 bc[16];
            #pragma unroll
            for (int ks = 0; ks < 16; ++ks) bc[ks] = ld_act(c1p + (size_t)(ks * 4 + wv) * 1024);
            #pragma unroll
            for (int ks = 0; ks < 16; ++ks) {
                const char* at = lds + L2W_OFF + (size_t)(ks * 3) * 1024 + (size_t)l * 16;
                a20 = __builtin_amdgcn_mfma_f32_16x16x32_f16(*(const half8*)(at       ), bc[ks], a20, 0, 0, 0);
                a21 = __builtin_amdgcn_mfma_f32_16x16x32_f16(*(const half8*)(at + 1024), bc[ks], a21, 0, 0, 0);
                a22 = __builtin_amdgcn_mfma_f32_16x16x32_f16(*(const half8*)(at + 2048), bc[ks], a22, 0, 0, 0);
            }
            const char* h2p = wsb + H2S_OFF + (size_t)rd * 90112u + (size_t)l * 16;
            half8 bh2[22];
            #pragma unroll
            for (int kk = 0; kk < 22; ++kk) bh2[kk] = ld_act(h2p + (size_t)(kk * 4 + wv) * 1024);
            #pragma unroll
            for (int kk = 0; kk < 22; ++kk) {
                const char* at = lds + L2W_OFF + (size_t)((16 + kk) * 3) * 1024 + (size_t)l * 16;
                a20 = __builtin_amdgcn_mfma_f32_16x16x32_f16(*(const half8*)(at       ), bh2[kk], a20, 0, 0, 0);
                a21 = __builtin_amdgcn_mfma_f32_16x16x32_f16(*(const half8*)(at + 1024), bh2[kk], a21, 0, 0, 0);
                a22 = __builtin_amdgcn_mfma_f32_16x16x32_f16(*(const half8*)(at + 2048), bh2[kk], a22, 0, 0, 0);
            }
            float cn2[3], hn2[3];
            #pragma unroll
            for (int q = 0; q < 3; ++q) {
                const f32x4 a = (q == 0) ? a20 : (q == 1) ? a21 : a22;
                const float ig = sigf(a[0] + bs2[q][0]);
                const float fg = sigf(a[1] + bs2[q][1]);
                const float gg = tanhf(a[2] + bs2[q][2]);
                const float og = sigf(a[3] + bs2[q][3]);
                const float c = fg * cr2[q] + ig * gg;
                cr2[q] = c;
                cn2[q] = c; hn2[q] = og * tanhf(c);
            }
            char* h2w = wsb + H2S_OFF + (size_t)wr * 90112u;
            #pragma unroll
            for (int q = 0; q < 3; ++q) {
                const float h0 = __shfl(hn2[q], lo), h1v = __shfl(hn2[q], 16 + lo);
                const float h2v = __shfl(hn2[q], 32 + lo), h3 = __shfl(hn2[q], 48 + lo);
                const float c0 = __shfl(cn2[q], lo), c1v = __shfl(cn2[q], 16 + lo);
                const float c2v = __shfl(cn2[q], 32 + lo), c3 = __shfl(cn2[q], 48 + lo);
                if (hi == q) {
                    const int cc = bk * 12 + q * 4;
                    if (cc + 4 <= OO) {
                        astore8(h2w + slab_waddr(cc, b), pack4h(h0, h1v, h2v, h3));
                        pend[0] = c0; pend[1] = c1v; pend[2] = c2v; pend[3] = c3;
                        pendP = out + (size_t)b * (TT * OO) + (size_t)(s - 1) * OO + cc;
                    }
                }
            }
        }
        // ---- single-hop arrival: one relaxed epoch store, no RMW, no flag ----
        __syncthreads();   // all waves' slab stores drained (vmcnt(0) per wave)
        if (s < TT && tid == 0) astore32(bar + bk, (unsigned)(s + 1));
        // ---- deferred out store: HBM ack drains behind the next wait ----
        if (pendP) {
            const f32x4 q4 = {pend[0], pend[1], pend[2], pend[3]};
            __builtin_nontemporal_store(q4, (f32x4*)pendP);
        }
    }
}

extern "C" void kernel_launch(void* const* d_in, const int* in_sizes, int n_in,
                              void* d_out, int out_size, void* d_ws, size_t ws_size,
                              hipStream_t stream)
{
    const float* data = (const float*)d_in[0];
    const float* Wih1 = (const float*)d_in[1];
    const float* Whh1 = (const float*)d_in[2];
    const float* bih1 = (const float*)d_in[3];
    const float* bhh1 = (const float*)d_in[4];
    const float* Wih2 = (const float*)d_in[5];
    const float* Whh2 = (const float*)d_in[6];
    const float* bih2 = (const float*)d_in[7];
    const float* bhh2 = (const float*)d_in[8];
    float* out = (float*)d_out;
    char* wsb  = (char*)d_ws;

    hipFuncSetAttribute((const void*)rnn_merged, hipFuncAttributeMaxDynamicSharedMemorySize, (int)LDS_BYTES);
    hipMemsetAsync(wsb, 0, MEMSET_BYTES, stream);   // slabs + epoch slots: replay-safe
    rnn_merged<<<NBLK, 256, LDS_BYTES, stream>>>(data,
                                                 Wih1, Whh1, bih1, bhh1,
                                                 Wih2, Whh2, bih2, bhh2,
                                                 wsb, out);
}